// Round 15
// baseline (230.719 us; speedup 1.0000x reference)
//
#include <hip/hip_runtime.h>

// Per-row exact top-k (k=1433 of N=2048) mask: out = adj * mask.
// Round 9 (6th resubmit after broker/container failures): three block-per-row
// kernels all pinned at 79.8 us with every pipe <35% busy => latency-bound on
// the per-row serial chain with only ~6-8 rows in flight per CU. Restructure:
// ONE WAVE PER ROW (64 lanes x 32 elems), all reductions intra-wave
// (shfl/ballot), per-wave-private LDS histogram, one barrier total => 32
// independent rows in flight per CU. Same HW-verified bracket math as round
// 8: ballot-count x>=T_HI, 64-slice histogram of [T_LO,T_HI), intra-wave
// ballot radix over crossing-slice survivors; exact fallback for any data
// (stable lowest-index-first ties, matching jax.lax.top_k).

static constexpr int ROW_N   = 2048;
static constexpr int K_KEEP  = 1433;   // max(1, int(2048 * (1.0 - 0.3)))
static constexpr int THREADS = 256;
static constexpr int WAVES   = 4;
static constexpr int VPL     = 8;      // float4 loads per lane (32 elems/lane)
static constexpr int NSLICE  = 64;

static constexpr float T_LO      = -0.72f;         // P(x>=T_LO)*2048 ~ 1565 > k
static constexpr float T_HI      = -0.33f;         // P(x>=T_HI)*2048 ~ 1289 < k
static constexpr float SLICE_INV = 164.1025641f;   // NSLICE / (T_HI - T_LO)

// Order-preserving fp32 <-> uint mapping (larger float => larger uint)
__device__ __forceinline__ unsigned ord_f32(float f) {
    unsigned b = __float_as_uint(f);
    unsigned m = (unsigned)((int)b >> 31);
    return b ^ (m | 0x80000000u);
}
__device__ __forceinline__ float unord_f32(unsigned o) {
    return __uint_as_float((o & 0x80000000u) ? (o & 0x7fffffffu) : ~o);
}
// Monotone non-decreasing for x >= T_LO.
__device__ __forceinline__ int slice_of(float x) {
    int i = (int)((x - T_LO) * SLICE_INV);
    return (i > NSLICE - 1) ? NSLICE - 1 : i;
}

__global__ __launch_bounds__(THREADS)
void topk_row_mask(const float* __restrict__ in, float* __restrict__ out) {
    __shared__ unsigned sh_hist[WAVES][NSLICE];
    __shared__ unsigned sh_buf[WAVES][64];
    __shared__ unsigned sh_ctr[WAVES];

    const int t    = threadIdx.x;
    const int lane = t & 63;
    const int w    = t >> 6;
    const long long row = (long long)blockIdx.x * WAVES + w;

    const float4* rin  = reinterpret_cast<const float4*>(in)  + row * (ROW_N / 4);
    float4*       rout = reinterpret_cast<float4*>(out)       + row * (ROW_N / 4);

    // 8 coalesced float4 loads per lane, all in flight together
    float4 v[VPL];
    #pragma unroll
    for (int j = 0; j < VPL; ++j) v[j] = rin[j * 64 + lane];

    sh_hist[w][lane] = 0u;         // lane<64 covers this wave's 64 bins
    if (lane == 0) sh_ctr[w] = 0u;
    __syncthreads();               // the only block-wide barrier

    // ---- count x >= T_HI per lane, wave all-reduce (no LDS histogram) ----
    unsigned chi = 0;
    #pragma unroll
    for (int j = 0; j < VPL; ++j) {
        const float4 q = v[j];
        chi += (q.x >= T_HI) + (q.y >= T_HI) + (q.z >= T_HI) + (q.w >= T_HI);
    }
    #pragma unroll
    for (int d = 1; d < 64; d <<= 1) chi += __shfl_xor(chi, d);

    // ---- in-bracket slice histogram (wave-private; ~276 atomics/row) ----
    #pragma unroll
    for (int j = 0; j < VPL; ++j) {
        const float4 q = v[j];
        #pragma unroll
        for (int c = 0; c < 4; ++c) {
            const float xv = (&q.x)[c];
            if (xv >= T_LO && xv < T_HI)
                atomicAdd(&sh_hist[w][slice_of(xv)], 1u);
        }
    }

    // ---- intra-wave suffix scan of the 64 slices ----
    const unsigned h = sh_hist[w][lane];
    unsigned s = h;
    #pragma unroll
    for (int d = 1; d < 64; d <<= 1) {
        unsigned o = __shfl_down(s, d);
        s += (lane + d < 64) ? o : 0u;
    }
    const unsigned Sl = chi + s;       // #elements >= lower edge of my slice
    const unsigned Sn = Sl - h;        // #elements >= upper edge
    const unsigned long long cb =
        __ballot(Sl >= (unsigned)K_KEEP && Sn < (unsigned)K_KEEP);

    unsigned tu = 0u, kq = 0u, cnteq = 0u;
    bool ok = (cb != 0ULL);            // wave-uniform
    if (ok) {
        const int sl = __ffsll((unsigned long long)cb) - 1;  // crossing slice
        const unsigned krem = (unsigned)K_KEEP - __shfl(Sn, sl);
        const unsigned cnt  = __shfl(h, sl);
        if (cnt <= 64u) {
            // compact crossing-slice survivors (~5) into wave-private buffer
            #pragma unroll
            for (int j = 0; j < VPL; ++j) {
                const float4 q = v[j];
                #pragma unroll
                for (int c = 0; c < 4; ++c) {
                    const float xv = (&q.x)[c];
                    if (xv >= T_LO && xv < T_HI && slice_of(xv) == sl) {
                        unsigned p = atomicAdd(&sh_ctr[w], 1u);
                        sh_buf[w][p] = ord_f32(xv);
                    }
                }
            }
            unsigned vv = (lane < (int)cnt) ? sh_buf[w][lane] : 0u;
            bool act = (lane < (int)cnt);
            unsigned kr = krem;
            for (int bpos = 31; bpos >= 0; --bpos) {
                const bool bs = ((vv >> bpos) & 1u) != 0u;
                const unsigned c = (unsigned)__popcll(__ballot(act && bs));
                if (c >= kr) act = act && bs;
                else { kr -= c; act = act && !bs; }
            }
            const unsigned long long eq = __ballot(act);
            cnteq = (unsigned)__popcll(eq);
            tu = __shfl(vv, __ffsll((unsigned long long)eq) - 1);
            kq = kr;
        } else {
            ok = false;   // oversized slice (adversarial) -> full fallback
        }
    }
    if (!ok) {
        // exact fallback: 32-bit radix over all 2048 elems, wave-reduced counts
        unsigned kr = (unsigned)K_KEEP, pfx = 0u;
        for (int bpos = 31; bpos >= 0; --bpos) {
            unsigned cl = 0;
            #pragma unroll
            for (int j = 0; j < VPL; ++j) {
                const float4 q = v[j];
                #pragma unroll
                for (int c = 0; c < 4; ++c) {
                    const unsigned uj = ord_f32((&q.x)[c]);
                    cl += ((((uj ^ pfx) >> bpos) >> 1) == 0u) &
                          ((uj >> bpos) & 1u);
                }
            }
            #pragma unroll
            for (int d = 1; d < 64; d <<= 1) cl += __shfl_xor(cl, d);
            if (cl >= kr) pfx |= (1u << bpos);
            else          kr -= cl;
        }
        unsigned cl = 0;
        #pragma unroll
        for (int j = 0; j < VPL; ++j) {
            const float4 q = v[j];
            #pragma unroll
            for (int c = 0; c < 4; ++c)
                cl += (ord_f32((&q.x)[c]) == pfx) ? 1u : 0u;
        }
        #pragma unroll
        for (int d = 1; d < 64; d <<= 1) cl += __shfl_xor(cl, d);
        tu = pfx; kq = kr; cnteq = cl;
    }

    const float xth = unord_f32(tu);   // exact float threshold

    if (kq == cnteq) {
        // keep = (x >= xth); no tie ranking needed (common path)
        #pragma unroll
        for (int j = 0; j < VPL; ++j) {
            float4 q = v[j];
            q.x = (q.x >= xth) ? q.x : 0.0f;
            q.y = (q.y >= xth) ? q.y : 0.0f;
            q.z = (q.z >= xth) ? q.z : 0.0f;
            q.w = (q.w >= xth) ? q.w : 0.0f;
            rout[j * 64 + lane] = q;
        }
    } else {
        // rare: stable rank among equals in element order p=(j*64+lane)*4+c,
        // keep lowest-index kq of them (matches jax.lax.top_k)
        unsigned base = 0;
        #pragma unroll
        for (int j = 0; j < VPL; ++j) {
            const float4 q = v[j];
            unsigned em = 0;
            #pragma unroll
            for (int c = 0; c < 4; ++c)
                em |= ((&q.x)[c] == xth) ? (1u << c) : 0u;
            const unsigned ec = __popc(em);
            unsigned ps = ec;   // wave inclusive scan over lanes
            #pragma unroll
            for (int d = 1; d < 64; d <<= 1) {
                unsigned o = __shfl_up(ps, d);
                ps += (lane >= d) ? o : 0u;
            }
            const unsigned mybase = base + ps - ec;
            float4 o4;
            unsigned seen = 0;
            #pragma unroll
            for (int c = 0; c < 4; ++c) {
                const float xv = (&q.x)[c];
                bool keep;
                if (xv > xth)            keep = true;
                else if ((em >> c) & 1u) { keep = (mybase + seen) < kq; ++seen; }
                else                     keep = false;
                (&o4.x)[c] = keep ? xv : 0.0f;
            }
            rout[j * 64 + lane] = o4;
            base += __shfl(ps, 63);
        }
    }
}

extern "C" void kernel_launch(void* const* d_in, const int* in_sizes, int n_in,
                              void* d_out, int out_size, void* d_ws, size_t ws_size,
                              hipStream_t stream) {
    const float* in  = (const float*)d_in[0];
    float*       out = (float*)d_out;
    const int rows = in_sizes[0] / ROW_N;   // 8 * 2048 = 16384 (multiple of 4)
    hipLaunchKernelGGL(topk_row_mask, dim3(rows / WAVES), dim3(THREADS), 0,
                       stream, in, out);
}